// Round 1
// baseline (122.350 us; speedup 1.0000x reference)
//
#include <hip/hip_runtime.h>

// Problem constants (fixed by the reference):
//   B=128 graphs, n=64 nodes/graph, E=65536 edges, K=16, D=64
//   e_full = B*n*n = 524288
#define EF      524288
#define NEDGE   65536
#define KDIM    16
#define DDIM    64

// ---------------------------------------------------------------------------
// Output 0: full_edge_index [2, EF], written as float32 values.
// j -> g = j>>12, rem = j&4095, r = rem>>6, c = rem&63
// row = g*64 + r, col = g*64 + c
// ---------------------------------------------------------------------------
__global__ __launch_bounds__(256) void fill_idx(float* __restrict__ out) {
    int gid = blockIdx.x * 256 + threadIdx.x;      // 131072 threads, 4 j's each
    int j0 = gid << 2;
    float rv[4], cv[4];
#pragma unroll
    for (int i = 0; i < 4; ++i) {
        int j = j0 + i;
        int g = j >> 12;
        int rem = j & 4095;
        rv[i] = (float)((g << 6) + (rem >> 6));
        cv[i] = (float)((g << 6) + (rem & 63));
    }
    *reinterpret_cast<float4*>(out + j0)      = make_float4(rv[0], rv[1], rv[2], rv[3]);
    *reinterpret_cast<float4*>(out + EF + j0) = make_float4(cv[0], cv[1], cv[2], cv[3]);
}

// ---------------------------------------------------------------------------
// out_val[j][:] = poly_val[j][:] @ W^T    (dense write of every row)
// 16 threads per row; thread t computes outputs [4t, 4t+3].
// W ([64][16] row-major) staged in LDS with stride 17 to kill bank conflicts:
// bank = (68t + 17i + k) mod 32 = (4t + 17i + k) mod 32 -> max 2-way (free).
// ---------------------------------------------------------------------------
__global__ __launch_bounds__(256) void pv_gemm(const float* __restrict__ pv,
                                               const float* __restrict__ W,
                                               float* __restrict__ outv) {
    __shared__ float sW[DDIM * 17];
    int tid = threadIdx.x;
    {
        // 256 threads load 1024 floats: thread loads 4 consecutive of row (tid>>2)
        int r = tid >> 2;
        int c = (tid & 3) << 2;
        float4 w = *reinterpret_cast<const float4*>(W + r * KDIM + c);
        float* d = &sW[r * 17 + c];
        d[0] = w.x; d[1] = w.y; d[2] = w.z; d[3] = w.w;
    }
    __syncthreads();

    long gid = (long)blockIdx.x * 256 + tid;
    long j = gid >> 4;           // row index in [0, EF)
    int  t = (int)(gid & 15);    // which 4-output chunk

    const float4* p = reinterpret_cast<const float4*>(pv + j * KDIM);
    float4 a0 = p[0], a1 = p[1], a2 = p[2], a3 = p[3];

    float res[4];
#pragma unroll
    for (int i = 0; i < 4; ++i) {
        const float* w = &sW[(t * 4 + i) * 17];
        float acc = a0.x * w[0]  + a0.y * w[1]  + a0.z * w[2]  + a0.w * w[3]
                  + a1.x * w[4]  + a1.y * w[5]  + a1.z * w[6]  + a1.w * w[7]
                  + a2.x * w[8]  + a2.y * w[9]  + a2.z * w[10] + a2.w * w[11]
                  + a3.x * w[12] + a3.y * w[13] + a3.z * w[14] + a3.w * w[15];
        res[i] = acc;
    }
    *reinterpret_cast<float4*>(outv + j * DDIM + t * 4) =
        make_float4(res[0], res[1], res[2], res[3]);
}

// ---------------------------------------------------------------------------
// Scatter-add edge_attr into slot(edge_index). Duplicate slots possible ->
// float atomics (device-scope by default on gfx950).
// slot = (r>>6)<<12 | (r&63)<<6 | (c&63)
// ---------------------------------------------------------------------------
__global__ __launch_bounds__(256) void scatter_edges(const float* __restrict__ ea,
                                                     const int* __restrict__ ei,
                                                     float* __restrict__ outv) {
    int gid = blockIdx.x * 256 + threadIdx.x;   // NEDGE*16 threads
    int e = gid >> 4;
    int t = gid & 15;
    int r = ei[e];
    int c = ei[NEDGE + e];
    long slot = ((long)(r >> 6) << 12) + ((long)(r & 63) << 6) + (long)(c & 63);
    float4 v = *reinterpret_cast<const float4*>(ea + (long)e * DDIM + t * 4);
    float* dst = outv + slot * DDIM + t * 4;
    atomicAdd(dst + 0, v.x);
    atomicAdd(dst + 1, v.y);
    atomicAdd(dst + 2, v.z);
    atomicAdd(dst + 3, v.w);
}

extern "C" void kernel_launch(void* const* d_in, const int* in_sizes, int n_in,
                              void* d_out, int out_size, void* d_ws, size_t ws_size,
                              hipStream_t stream) {
    const float* poly_val  = (const float*)d_in[0];   // [EF, 16]
    const float* edge_attr = (const float*)d_in[1];   // [NEDGE, 64]
    const float* W         = (const float*)d_in[2];   // [64, 16]
    // d_in[3] = poly_idx (identity slot order -> unused)
    const int*   edge_index = (const int*)d_in[4];    // [2, NEDGE]
    // d_in[5] = batch, d_in[6] = num_graphs (unused; constants fixed)

    float* out  = (float*)d_out;          // [2*EF] indices as f32, then out_val
    float* outv = out + 2 * (long)EF;     // [EF, 64]

    // Output 0: index pattern (independent of other kernels)
    fill_idx<<<EF / 4 / 256, 256, 0, stream>>>(out);

    // out_val = poly_val @ W^T  (writes every element -> no zero-init needed)
    pv_gemm<<<(EF * 16) / 256, 256, 0, stream>>>(poly_val, W, outv);

    // += scatter of real edges (same stream -> ordered after pv_gemm)
    scatter_edges<<<(NEDGE * 16) / 256, 256, 0, stream>>>(edge_attr, edge_index, outv);
}